// Round 1
// baseline (792.201 us; speedup 1.0000x reference)
//
#include <hip/hip_runtime.h>

#define TOK 2048
#define DDIM 1024
#define HDIM 1408
#define ENUM 8
#define TM 64
#define TN 64
#define BK 16

__device__ __forceinline__ float silu_f(float g) {
    return g / (1.0f + __expf(-g));
}

// One wave (64 threads) per token: 8 logits, softmax, top-2, append to expert lists.
__global__ __launch_bounds__(64) void gate_kernel(
    const float* __restrict__ x, const float* __restrict__ gw,
    int* __restrict__ counts, int* __restrict__ toks, float* __restrict__ wts)
{
    const int t = blockIdx.x;
    const int lane = threadIdx.x;
    const float* xr = x + (size_t)t * DDIM;
    float xv[16];
#pragma unroll
    for (int i = 0; i < 16; ++i) xv[i] = xr[lane + 64 * i];
    float logit[ENUM];
#pragma unroll
    for (int e = 0; e < ENUM; ++e) {
        const float* gr = gw + (size_t)e * DDIM;
        float acc = 0.f;
#pragma unroll
        for (int i = 0; i < 16; ++i) acc += xv[i] * gr[lane + 64 * i];
#pragma unroll
        for (int s = 32; s > 0; s >>= 1) acc += __shfl_xor(acc, s, 64);
        logit[e] = acc;
    }
    if (lane == 0) {
        float mx = logit[0];
#pragma unroll
        for (int e = 1; e < ENUM; ++e) mx = fmaxf(mx, logit[e]);
        float p[ENUM]; float se = 0.f;
#pragma unroll
        for (int e = 0; e < ENUM; ++e) { p[e] = __expf(logit[e] - mx); se += p[e]; }
        float inv = 1.0f / se;
#pragma unroll
        for (int e = 0; e < ENUM; ++e) p[e] *= inv;
        int i0 = 0;
#pragma unroll
        for (int e = 1; e < ENUM; ++e) if (p[e] > p[i0]) i0 = e;
        int i1 = (i0 == 0) ? 1 : 0;
#pragma unroll
        for (int e = 0; e < ENUM; ++e) if (e != i0 && p[e] > p[i1]) i1 = e;
        int pos0 = atomicAdd(&counts[i0], 1);
        toks[i0 * TOK + pos0] = (t << 1);        // slot = 2t + rank
        wts[i0 * TOK + pos0] = p[i0];
        int pos1 = atomicAdd(&counts[i1], 1);
        toks[i1 * TOK + pos1] = (t << 1) | 1;
        wts[i1 * TOK + pos1] = p[i1];
    }
}

// Grouped GEMM1 (fused g,u,silu): Hbuf[slot] = silu(x@w1g[e]) * (x@w1u[e])
__global__ __launch_bounds__(256) void up_kernel(
    const float* __restrict__ x, const float* __restrict__ w1g,
    const float* __restrict__ w1u, const int* __restrict__ counts,
    const int* __restrict__ toks, float* __restrict__ Hbuf)
{
    const int e = blockIdx.z;
    const int cnt = counts[e];
    const int m0 = blockIdx.y * TM;
    if (m0 >= cnt) return;
    const int n0 = blockIdx.x * TN;
    const int tid = threadIdx.x;
    const int tx = tid & 15, ty = tid >> 4;

    __shared__ float Xs[TM][BK + 1];
    __shared__ float Gs[BK][TN];
    __shared__ float Us[BK][TN];
    __shared__ int rowslot[TM];

    if (tid < TM) {
        int r = m0 + tid;
        rowslot[tid] = (r < cnt) ? toks[e * TOK + r] : -1;
    }
    __syncthreads();

    const int lr = tid >> 2;
    const int lk = (tid & 3) * 4;
    const int slotA = rowslot[lr];
    const float* xptr = x + (size_t)(slotA < 0 ? 0 : (slotA >> 1)) * DDIM + lk;

    const int wr = tid >> 4;
    const int wc = (tid & 15) * 4;
    const float* gptr = w1g + ((size_t)e * DDIM + wr) * HDIM + n0 + wc;
    const float* uptr = w1u + ((size_t)e * DDIM + wr) * HDIM + n0 + wc;

    float accg[4][4] = {{0.f}}, accu[4][4] = {{0.f}};

    for (int k0 = 0; k0 < DDIM; k0 += BK) {
        float4 xa = *(const float4*)(xptr + k0);
        float4 ga = *(const float4*)(gptr + (size_t)k0 * HDIM);
        float4 ua = *(const float4*)(uptr + (size_t)k0 * HDIM);
        __syncthreads();
        Xs[lr][lk + 0] = xa.x;
        Xs[lr][lk + 1] = xa.y;
        Xs[lr][lk + 2] = xa.z;
        Xs[lr][lk + 3] = xa.w;
        *(float4*)&Gs[wr][wc] = ga;
        *(float4*)&Us[wr][wc] = ua;
        __syncthreads();
#pragma unroll
        for (int kk = 0; kk < BK; ++kk) {
            float a[4];
#pragma unroll
            for (int i = 0; i < 4; ++i) a[i] = Xs[ty * 4 + i][kk];
            float4 bg = *(const float4*)&Gs[kk][tx * 4];
            float4 bu = *(const float4*)&Us[kk][tx * 4];
            const float bgv[4] = {bg.x, bg.y, bg.z, bg.w};
            const float buv[4] = {bu.x, bu.y, bu.z, bu.w};
#pragma unroll
            for (int i = 0; i < 4; ++i) {
#pragma unroll
                for (int j = 0; j < 4; ++j) {
                    accg[i][j] += a[i] * bgv[j];
                    accu[i][j] += a[i] * buv[j];
                }
            }
        }
    }
#pragma unroll
    for (int i = 0; i < 4; ++i) {
        int r = ty * 4 + i;
        int slot = rowslot[r];
        if (slot < 0) continue;
        float4 hv;
        hv.x = silu_f(accg[i][0]) * accu[i][0];
        hv.y = silu_f(accg[i][1]) * accu[i][1];
        hv.z = silu_f(accg[i][2]) * accu[i][2];
        hv.w = silu_f(accg[i][3]) * accu[i][3];
        *(float4*)(Hbuf + (size_t)slot * HDIM + n0 + tx * 4) = hv;
    }
}

// Grouped GEMM2: y[t] += wt * (Hbuf[slot] @ w2[e])
__global__ __launch_bounds__(256) void down_kernel(
    const float* __restrict__ Hbuf, const float* __restrict__ w2,
    const int* __restrict__ counts, const int* __restrict__ toks,
    const float* __restrict__ wts, float* __restrict__ y)
{
    const int e = blockIdx.z;
    const int cnt = counts[e];
    const int m0 = blockIdx.y * TM;
    if (m0 >= cnt) return;
    const int n0 = blockIdx.x * TN;
    const int tid = threadIdx.x;
    const int tx = tid & 15, ty = tid >> 4;

    __shared__ float As[TM][BK + 1];
    __shared__ float Bs[BK][TN];
    __shared__ int rowslot[TM];
    __shared__ float roww[TM];

    if (tid < TM) {
        int r = m0 + tid;
        rowslot[tid] = (r < cnt) ? toks[e * TOK + r] : -1;
        roww[tid] = (r < cnt) ? wts[e * TOK + r] : 0.f;
    }
    __syncthreads();

    const int lr = tid >> 2;
    const int lk = (tid & 3) * 4;
    const int slotA = rowslot[lr];
    const float* aptr = Hbuf + (size_t)(slotA < 0 ? 0 : slotA) * HDIM + lk;

    const int wr = tid >> 4;
    const int wc = (tid & 15) * 4;
    const float* bptr = w2 + ((size_t)e * HDIM + wr) * DDIM + n0 + wc;

    float acc[4][4] = {{0.f}};

    for (int k0 = 0; k0 < HDIM; k0 += BK) {
        float4 av = *(const float4*)(aptr + k0);
        float4 bv = *(const float4*)(bptr + (size_t)k0 * DDIM);
        __syncthreads();
        As[lr][lk + 0] = av.x;
        As[lr][lk + 1] = av.y;
        As[lr][lk + 2] = av.z;
        As[lr][lk + 3] = av.w;
        *(float4*)&Bs[wr][wc] = bv;
        __syncthreads();
#pragma unroll
        for (int kk = 0; kk < BK; ++kk) {
            float a[4];
#pragma unroll
            for (int i = 0; i < 4; ++i) a[i] = As[ty * 4 + i][kk];
            float4 b = *(const float4*)&Bs[kk][tx * 4];
            const float bv4[4] = {b.x, b.y, b.z, b.w};
#pragma unroll
            for (int i = 0; i < 4; ++i) {
#pragma unroll
                for (int j = 0; j < 4; ++j) acc[i][j] += a[i] * bv4[j];
            }
        }
    }
#pragma unroll
    for (int i = 0; i < 4; ++i) {
        int r = ty * 4 + i;
        int slot = rowslot[r];
        if (slot < 0) continue;
        int t = slot >> 1;
        float w = roww[r];
        float* yr = y + (size_t)t * DDIM + n0 + tx * 4;
#pragma unroll
        for (int j = 0; j < 4; ++j) atomicAdd(&yr[j], w * acc[i][j]);
    }
}

extern "C" void kernel_launch(void* const* d_in, const int* in_sizes, int n_in,
                              void* d_out, int out_size, void* d_ws, size_t ws_size,
                              hipStream_t stream) {
    const float* x   = (const float*)d_in[0];
    const float* gw  = (const float*)d_in[1];
    const float* w1g = (const float*)d_in[2];
    const float* w1u = (const float*)d_in[3];
    const float* w2  = (const float*)d_in[4];
    float* y = (float*)d_out;
    char* ws = (char*)d_ws;

    // workspace layout
    int*   counts = (int*)ws;                                  // 256 B (8 used)
    int*   toks   = (int*)(ws + 256);                          // E*T ints = 64 KB
    float* wts    = (float*)(ws + 256 + TOK * ENUM * 4);       // 64 KB
    float* Hbuf   = (float*)(ws + 256 + 2 * TOK * ENUM * 4);   // 2T x H fp32 = 23 MB

    hipMemsetAsync(counts, 0, 256, stream);
    hipMemsetAsync(y, 0, (size_t)TOK * DDIM * sizeof(float), stream);

    gate_kernel<<<TOK, 64, 0, stream>>>(x, gw, counts, toks, wts);

    dim3 g1(HDIM / TN, TOK / TM, ENUM);
    up_kernel<<<g1, 256, 0, stream>>>(x, w1g, w1u, counts, toks, Hbuf);

    dim3 g2(DDIM / TN, TOK / TM, ENUM);
    down_kernel<<<g2, 256, 0, stream>>>(Hbuf, w2, counts, toks, wts, y);
}

// Round 2
// 358.811 us; speedup vs baseline: 2.2078x; 2.2078x over previous
//
#include <hip/hip_runtime.h>

#define TOK 2048
#define DDIM 1024
#define HDIM 1408
#define ENUM 8
#define NSLOT (2 * TOK)

typedef unsigned int uint;
typedef unsigned short ushort;

using bf16x8 = __attribute__((ext_vector_type(8))) __bf16;
using f32x4  = __attribute__((ext_vector_type(4))) float;

__device__ __forceinline__ float silu_f(float g) {
    return g / (1.0f + __expf(-g));
}

__device__ __forceinline__ ushort cvt_bf16(float f) {
    uint u = __float_as_uint(f);
    u += 0x7FFFu + ((u >> 16) & 1u);   // RNE
    return (ushort)(u >> 16);
}

// ---------------- gate: one wave per token, softmax over 8 logits, top-2 ----
__global__ __launch_bounds__(64) void gate_kernel(
    const float* __restrict__ x, const float* __restrict__ gw,
    int* __restrict__ counts, int* __restrict__ toks, float* __restrict__ wts)
{
    const int t = blockIdx.x;
    const int lane = threadIdx.x;
    const float* xr = x + (size_t)t * DDIM;
    float xv[16];
#pragma unroll
    for (int i = 0; i < 16; ++i) xv[i] = xr[lane + 64 * i];
    float logit[ENUM];
#pragma unroll
    for (int e = 0; e < ENUM; ++e) {
        const float* gr = gw + (size_t)e * DDIM;
        float acc = 0.f;
#pragma unroll
        for (int i = 0; i < 16; ++i) acc += xv[i] * gr[lane + 64 * i];
#pragma unroll
        for (int s = 32; s > 0; s >>= 1) acc += __shfl_xor(acc, s, 64);
        logit[e] = acc;
    }
    if (lane == 0) {
        float mx = logit[0];
#pragma unroll
        for (int e = 1; e < ENUM; ++e) mx = fmaxf(mx, logit[e]);
        float p[ENUM]; float se = 0.f;
#pragma unroll
        for (int e = 0; e < ENUM; ++e) { p[e] = __expf(logit[e] - mx); se += p[e]; }
        float inv = 1.0f / se;
#pragma unroll
        for (int e = 0; e < ENUM; ++e) p[e] *= inv;
        int i0 = 0;
#pragma unroll
        for (int e = 1; e < ENUM; ++e) if (p[e] > p[i0]) i0 = e;
        int i1 = (i0 == 0) ? 1 : 0;
#pragma unroll
        for (int e = 0; e < ENUM; ++e) if (e != i0 && p[e] > p[i1]) i1 = e;
        int pos0 = atomicAdd(&counts[i0], 1);
        toks[i0 * TOK + pos0] = (t << 1);
        wts[i0 * TOK + pos0] = p[i0];
        int pos1 = atomicAdd(&counts[i1], 1);
        toks[i1 * TOK + pos1] = (t << 1) | 1;
        wts[i1 * TOK + pos1] = p[i1];
    }
}

// ---------------- cast x: fp32 [T][D] -> bf16 [T][D] -----------------------
__global__ __launch_bounds__(256) void cast_x_kernel(
    const float* __restrict__ src, ushort* __restrict__ dst)
{
    const size_t base = ((size_t)blockIdx.x * 256 + threadIdx.x) * 8;
    float4 a = *(const float4*)(src + base);
    float4 b = *(const float4*)(src + base + 4);
    ushort o[8];
    o[0] = cvt_bf16(a.x); o[1] = cvt_bf16(a.y); o[2] = cvt_bf16(a.z); o[3] = cvt_bf16(a.w);
    o[4] = cvt_bf16(b.x); o[5] = cvt_bf16(b.y); o[6] = cvt_bf16(b.z); o[7] = cvt_bf16(b.w);
    *(uint4*)(dst + base) = *(uint4*)o;
}

// ------- transpose-cast: src fp32 [E][K][N] -> packed bf16 B^T tiles -------
// dst[e][nb][ks][nn(128)][kk(32)] = src[e][ks*32+kk][nb*128+nn]
__global__ __launch_bounds__(256) void tcast_kernel(
    const float* __restrict__ src, ushort* __restrict__ dst, int N, int KS, int NB)
{
    const int ks = blockIdx.x, nb = blockIdx.y, e = blockIdx.z;
    const int tid = threadIdx.x;
    __shared__ float Ls[32][132];

    const float* st = src + (size_t)e * ((size_t)KS * 32) * N + (size_t)(ks * 32) * N + nb * 128;
    const int n4 = (tid & 31) * 4;
#pragma unroll
    for (int r = 0; r < 4; ++r) {
        int k = (tid >> 5) + r * 8;
        float4 v = *(const float4*)(st + (size_t)k * N + n4);
        Ls[k][n4 + 0] = v.x; Ls[k][n4 + 1] = v.y; Ls[k][n4 + 2] = v.z; Ls[k][n4 + 3] = v.w;
    }
    __syncthreads();

    ushort* dt = dst + ((((size_t)e * NB + nb) * KS) + ks) * 4096;
    const int nn = tid >> 1;
    const int kk0 = (tid & 1) * 16;
    ushort o[16];
#pragma unroll
    for (int j = 0; j < 16; ++j) o[j] = cvt_bf16(Ls[kk0 + j][nn]);
    *(uint4*)(dt + nn * 32 + kk0)     = *(uint4*)&o[0];
    *(uint4*)(dt + nn * 32 + kk0 + 8) = *(uint4*)&o[8];
}

// ---------------- up: Hbuf[slot] = silu(x@w1g[e]) * (x@w1u[e]), bf16 MFMA --
#define NB1 11
#define KS1 32
__global__ __launch_bounds__(256) void up_mfma(
    const ushort* __restrict__ xb, const ushort* __restrict__ BgP,
    const ushort* __restrict__ BuP, const int* __restrict__ counts,
    const int* __restrict__ toks, ushort* __restrict__ Hbuf)
{
    const int e = blockIdx.z;
    const int cnt = counts[e];
    const int m0 = blockIdx.y * 64;
    if (m0 >= cnt) return;
    const int nb = blockIdx.x;
    const int tid = threadIdx.x;

    __shared__ ushort As[64][40];
    __shared__ ushort Bgs[128][40];
    __shared__ ushort Bus[128][40];
    __shared__ int rowslot[64];

    if (tid < 64) {
        int r = m0 + tid;
        rowslot[tid] = (r < cnt) ? toks[e * TOK + r] : -1;
    }
    __syncthreads();

    // staging addresses
    const int ar = tid >> 2;            // A row 0..63
    const int ac = (tid & 3) * 8;       // A col (elements)
    const int aslot = rowslot[ar];
    const ushort* aptr = xb + (size_t)(aslot < 0 ? 0 : (aslot >> 1)) * DDIM + ac;
    const ushort* bgptr = BgP + ((size_t)(e * NB1 + nb) * KS1) * 4096 + tid * 16;
    const ushort* buptr = BuP + ((size_t)(e * NB1 + nb) * KS1) * 4096 + tid * 16;
    const int bn = tid >> 1;            // B row 0..127
    const int bk = (tid & 1) * 16;      // B col (elements)

    const int w = tid >> 6;             // wave 0..3 -> n offset w*32
    const int lane = tid & 63;
    const int q = lane >> 4;
    const int l15 = lane & 15;

    f32x4 accg[4][2], accu[4][2];
#pragma unroll
    for (int i = 0; i < 4; ++i)
#pragma unroll
        for (int j = 0; j < 2; ++j) { accg[i][j] = (f32x4)0.f; accu[i][j] = (f32x4)0.f; }

    for (int ks = 0; ks < KS1; ++ks) {
        uint4 av  = *(const uint4*)(aptr + ks * 32);
        uint4 bg0 = *(const uint4*)(bgptr + (size_t)ks * 4096);
        uint4 bg1 = *(const uint4*)(bgptr + (size_t)ks * 4096 + 8);
        uint4 bu0 = *(const uint4*)(buptr + (size_t)ks * 4096);
        uint4 bu1 = *(const uint4*)(buptr + (size_t)ks * 4096 + 8);
        __syncthreads();
        *(uint4*)&As[ar][ac] = av;
        *(uint4*)&Bgs[bn][bk] = bg0;
        *(uint4*)&Bgs[bn][bk + 8] = bg1;
        *(uint4*)&Bus[bn][bk] = bu0;
        *(uint4*)&Bus[bn][bk + 8] = bu1;
        __syncthreads();

        bf16x8 a[4], bg[2], bu[2];
#pragma unroll
        for (int mi = 0; mi < 4; ++mi)
            a[mi] = *(const bf16x8*)&As[mi * 16 + l15][q * 8];
#pragma unroll
        for (int ni = 0; ni < 2; ++ni) {
            bg[ni] = *(const bf16x8*)&Bgs[w * 32 + ni * 16 + l15][q * 8];
            bu[ni] = *(const bf16x8*)&Bus[w * 32 + ni * 16 + l15][q * 8];
        }
#pragma unroll
        for (int mi = 0; mi < 4; ++mi)
#pragma unroll
            for (int ni = 0; ni < 2; ++ni) {
                accg[mi][ni] = __builtin_amdgcn_mfma_f32_16x16x32_bf16(a[mi], bg[ni], accg[mi][ni], 0, 0, 0);
                accu[mi][ni] = __builtin_amdgcn_mfma_f32_16x16x32_bf16(a[mi], bu[ni], accu[mi][ni], 0, 0, 0);
            }
    }

    // epilogue: h = silu(g)*u -> bf16 Hbuf[slot][n]
#pragma unroll
    for (int mi = 0; mi < 4; ++mi) {
#pragma unroll
        for (int r = 0; r < 4; ++r) {
            int ml = mi * 16 + q * 4 + r;
            int slot = rowslot[ml];
            if (slot < 0) continue;
            ushort* hrow = Hbuf + (size_t)slot * HDIM + nb * 128 + w * 32 + l15;
#pragma unroll
            for (int ni = 0; ni < 2; ++ni) {
                float g = accg[mi][ni][r];
                float u = accu[mi][ni][r];
                hrow[ni * 16] = cvt_bf16(silu_f(g) * u);
            }
        }
    }
}

// ---------------- down: y[t] += wt * (Hbuf[slot] @ w2[e]) ------------------
#define NB2 8
#define KS2 44
__global__ __launch_bounds__(256) void down_mfma(
    const ushort* __restrict__ Hbuf, const ushort* __restrict__ W2P,
    const int* __restrict__ counts, const int* __restrict__ toks,
    const float* __restrict__ wts, float* __restrict__ y)
{
    const int e = blockIdx.z;
    const int cnt = counts[e];
    const int m0 = blockIdx.y * 64;
    if (m0 >= cnt) return;
    const int nb = blockIdx.x;
    const int tid = threadIdx.x;

    __shared__ ushort As[64][40];
    __shared__ ushort Bs[128][40];
    __shared__ int rowslot[64];
    __shared__ float roww[64];

    if (tid < 64) {
        int r = m0 + tid;
        rowslot[tid] = (r < cnt) ? toks[e * TOK + r] : -1;
        roww[tid] = (r < cnt) ? wts[e * TOK + r] : 0.f;
    }
    __syncthreads();

    const int ar = tid >> 2;
    const int ac = (tid & 3) * 8;
    const int aslot = rowslot[ar];
    const ushort* aptr = Hbuf + (size_t)(aslot < 0 ? 0 : aslot) * HDIM + ac;
    const ushort* bptr = W2P + ((size_t)(e * NB2 + nb) * KS2) * 4096 + tid * 16;
    const int bn = tid >> 1;
    const int bk = (tid & 1) * 16;

    const int w = tid >> 6;
    const int lane = tid & 63;
    const int q = lane >> 4;
    const int l15 = lane & 15;

    f32x4 acc[4][2];
#pragma unroll
    for (int i = 0; i < 4; ++i)
#pragma unroll
        for (int j = 0; j < 2; ++j) acc[i][j] = (f32x4)0.f;

    for (int ks = 0; ks < KS2; ++ks) {
        uint4 av = *(const uint4*)(aptr + ks * 32);
        uint4 b0 = *(const uint4*)(bptr + (size_t)ks * 4096);
        uint4 b1 = *(const uint4*)(bptr + (size_t)ks * 4096 + 8);
        __syncthreads();
        *(uint4*)&As[ar][ac] = av;
        *(uint4*)&Bs[bn][bk] = b0;
        *(uint4*)&Bs[bn][bk + 8] = b1;
        __syncthreads();

        bf16x8 a[4], b[2];
#pragma unroll
        for (int mi = 0; mi < 4; ++mi)
            a[mi] = *(const bf16x8*)&As[mi * 16 + l15][q * 8];
#pragma unroll
        for (int ni = 0; ni < 2; ++ni)
            b[ni] = *(const bf16x8*)&Bs[w * 32 + ni * 16 + l15][q * 8];
#pragma unroll
        for (int mi = 0; mi < 4; ++mi)
#pragma unroll
            for (int ni = 0; ni < 2; ++ni)
                acc[mi][ni] = __builtin_amdgcn_mfma_f32_16x16x32_bf16(a[mi], b[ni], acc[mi][ni], 0, 0, 0);
    }

#pragma unroll
    for (int mi = 0; mi < 4; ++mi) {
#pragma unroll
        for (int r = 0; r < 4; ++r) {
            int ml = mi * 16 + q * 4 + r;
            int slot = rowslot[ml];
            if (slot < 0) continue;
            float wt = roww[ml];
            float* yr = y + (size_t)(slot >> 1) * DDIM + nb * 128 + w * 32 + l15;
#pragma unroll
            for (int ni = 0; ni < 2; ++ni)
                atomicAdd(&yr[ni * 16], wt * acc[mi][ni][r]);
        }
    }
}

extern "C" void kernel_launch(void* const* d_in, const int* in_sizes, int n_in,
                              void* d_out, int out_size, void* d_ws, size_t ws_size,
                              hipStream_t stream) {
    const float* x   = (const float*)d_in[0];
    const float* gw  = (const float*)d_in[1];
    const float* w1g = (const float*)d_in[2];
    const float* w1u = (const float*)d_in[3];
    const float* w2  = (const float*)d_in[4];
    float* y = (float*)d_out;
    char* ws = (char*)d_ws;

    // workspace layout (all offsets 256B aligned)
    int*    counts = (int*)ws;                                  //     256 B
    int*    toks   = (int*)(ws + 256);                          //  65536 B
    float*  wts    = (float*)(ws + 256 + 65536);                //  65536 B
    size_t  off = 256 + 2 * 65536;                              // 131328
    ushort* xb   = (ushort*)(ws + off);  off += (size_t)TOK * DDIM * 2;        // 4 MB
    ushort* BgP  = (ushort*)(ws + off);  off += (size_t)ENUM * DDIM * HDIM * 2; // 22 MB
    ushort* BuP  = (ushort*)(ws + off);  off += (size_t)ENUM * DDIM * HDIM * 2; // 22 MB
    ushort* W2P  = (ushort*)(ws + off);  off += (size_t)ENUM * HDIM * DDIM * 2; // 22 MB
    ushort* Hbuf = (ushort*)(ws + off);                                         // 11 MB

    hipMemsetAsync(counts, 0, 256, stream);
    hipMemsetAsync(y, 0, (size_t)TOK * DDIM * sizeof(float), stream);

    gate_kernel<<<TOK, 64, 0, stream>>>(x, gw, counts, toks, wts);

    cast_x_kernel<<<(TOK * DDIM) / (256 * 8), 256, 0, stream>>>(x, xb);

    // w1g, w1u: [E][K=1024][N=1408] -> tiles; w2: [E][K=1408][N=1024]
    tcast_kernel<<<dim3(KS1, NB1, ENUM), 256, 0, stream>>>(w1g, BgP, HDIM, KS1, NB1);
    tcast_kernel<<<dim3(KS1, NB1, ENUM), 256, 0, stream>>>(w1u, BuP, HDIM, KS1, NB1);
    tcast_kernel<<<dim3(KS2, NB2, ENUM), 256, 0, stream>>>(w2,  W2P, DDIM, KS2, NB2);

    up_mfma<<<dim3(NB1, TOK / 64, ENUM), 256, 0, stream>>>(xb, BgP, BuP, counts, toks, Hbuf);
    down_mfma<<<dim3(NB2, TOK / 64, ENUM), 256, 0, stream>>>(Hbuf, W2P, counts, toks, wts, y);
}

// Round 4
// 330.518 us; speedup vs baseline: 2.3968x; 1.0856x over previous
//
#include <hip/hip_runtime.h>

#define TOK 2048
#define DDIM 1024
#define HDIM 1408
#define ENUM 8
#define NSLOT (2 * TOK)
#define NB1 22   // up:   HDIM / 64
#define KS1 32   // up:   DDIM / 32
#define NB2 8    // down: DDIM / 128
#define KS2 44   // down: HDIM / 32

typedef unsigned int uint;
typedef unsigned short ushort;

using bf16x8 = __attribute__((ext_vector_type(8))) __bf16;
using f32x4  = __attribute__((ext_vector_type(4))) float;

__device__ __forceinline__ float silu_f(float g) {
    return g / (1.0f + __expf(-g));
}

__device__ __forceinline__ ushort cvt_bf16(float f) {
    uint u = __float_as_uint(f);
    u += 0x7FFFu + ((u >> 16) & 1u);   // RNE
    return (ushort)(u >> 16);
}

// async global->LDS, 16 B per lane, wave-uniform LDS base + lane*16
__device__ __forceinline__ void gl2lds16(const void* g, void* l) {
    __builtin_amdgcn_global_load_lds(
        (const __attribute__((address_space(1))) uint*)g,
        (__attribute__((address_space(3))) uint*)l, 16, 0, 0);
}

// ---- gate: one wave/token; softmax top-2; also emits bf16 x row ----------
__global__ __launch_bounds__(64) void gate_kernel(
    const float* __restrict__ x, const float* __restrict__ gw,
    int* __restrict__ counts, int* __restrict__ toks,
    float* __restrict__ wslot, ushort* __restrict__ xb)
{
    const int t = blockIdx.x;
    const int lane = threadIdx.x;
    const float* xr = x + (size_t)t * DDIM;
    ushort* xbr = xb + (size_t)t * DDIM;
    float xv[16];
#pragma unroll
    for (int i = 0; i < 16; ++i) xv[i] = xr[lane + 64 * i];
#pragma unroll
    for (int i = 0; i < 16; ++i) xbr[lane + 64 * i] = cvt_bf16(xv[i]);
    float logit[ENUM];
#pragma unroll
    for (int e = 0; e < ENUM; ++e) {
        const float* gr = gw + (size_t)e * DDIM;
        float acc = 0.f;
#pragma unroll
        for (int i = 0; i < 16; ++i) acc += xv[i] * gr[lane + 64 * i];
#pragma unroll
        for (int s = 32; s > 0; s >>= 1) acc += __shfl_xor(acc, s, 64);
        logit[e] = acc;
    }
    if (lane == 0) {
        float mx = logit[0];
#pragma unroll
        for (int e = 1; e < ENUM; ++e) mx = fmaxf(mx, logit[e]);
        float p[ENUM]; float se = 0.f;
#pragma unroll
        for (int e = 0; e < ENUM; ++e) { p[e] = __expf(logit[e] - mx); se += p[e]; }
        float inv = 1.0f / se;
#pragma unroll
        for (int e = 0; e < ENUM; ++e) p[e] *= inv;
        int i0 = 0;
#pragma unroll
        for (int e = 1; e < ENUM; ++e) if (p[e] > p[i0]) i0 = e;
        int i1 = (i0 == 0) ? 1 : 0;
#pragma unroll
        for (int e = 0; e < ENUM; ++e) if (e != i0 && p[e] > p[i1]) i1 = e;
        int pos0 = atomicAdd(&counts[i0], 1);
        toks[i0 * TOK + pos0] = (t << 1);
        wslot[(t << 1)] = p[i0];
        int pos1 = atomicAdd(&counts[i1], 1);
        toks[i1 * TOK + pos1] = (t << 1) | 1;
        wslot[(t << 1) | 1] = p[i1];
    }
}

// ---- tcast64: fp32 [E][K][N] -> bf16 tiles [e][nb][ks][nn(64)][kk(32)] ----
__global__ __launch_bounds__(256) void tcast64_kernel(
    const float* __restrict__ src, ushort* __restrict__ dst, int N, int KS, int NB)
{
    const int ks = blockIdx.x, nb = blockIdx.y, e = blockIdx.z;
    const int tid = threadIdx.x;
    __shared__ float Ls[32][68];

    const float* st = src + (size_t)e * ((size_t)KS * 32) * N + (size_t)(ks * 32) * N + nb * 64;
    const int n4 = (tid & 15) * 4;
#pragma unroll
    for (int r = 0; r < 2; ++r) {
        int k = (tid >> 4) + r * 16;
        float4 v = *(const float4*)(st + (size_t)k * N + n4);
        Ls[k][n4 + 0] = v.x; Ls[k][n4 + 1] = v.y; Ls[k][n4 + 2] = v.z; Ls[k][n4 + 3] = v.w;
    }
    __syncthreads();

    ushort* dt = dst + ((((size_t)e * NB + nb) * KS) + ks) * 2048;
    const int nn = tid >> 2;
    const int kk0 = (tid & 3) * 8;
    ushort o[8];
#pragma unroll
    for (int j = 0; j < 8; ++j) o[j] = cvt_bf16(Ls[kk0 + j][nn]);
    *(uint4*)(dt + nn * 32 + kk0) = *(uint4*)o;
}

// ---- tcast128: fp32 [E][K][N] -> bf16 tiles [e][nb][ks][nn(128)][kk(32)] --
__global__ __launch_bounds__(256) void tcast128_kernel(
    const float* __restrict__ src, ushort* __restrict__ dst, int N, int KS, int NB)
{
    const int ks = blockIdx.x, nb = blockIdx.y, e = blockIdx.z;
    const int tid = threadIdx.x;
    __shared__ float Ls[32][132];

    const float* st = src + (size_t)e * ((size_t)KS * 32) * N + (size_t)(ks * 32) * N + nb * 128;
    const int n4 = (tid & 31) * 4;
#pragma unroll
    for (int r = 0; r < 4; ++r) {
        int k = (tid >> 5) + r * 8;
        float4 v = *(const float4*)(st + (size_t)k * N + n4);
        Ls[k][n4 + 0] = v.x; Ls[k][n4 + 1] = v.y; Ls[k][n4 + 2] = v.z; Ls[k][n4 + 3] = v.w;
    }
    __syncthreads();

    ushort* dt = dst + ((((size_t)e * NB + nb) * KS) + ks) * 4096;
    const int nn = tid >> 1;
    const int kk0 = (tid & 1) * 16;
    ushort o[16];
#pragma unroll
    for (int j = 0; j < 16; ++j) o[j] = cvt_bf16(Ls[kk0 + j][nn]);
    *(uint4*)(dt + nn * 32 + kk0)     = *(uint4*)&o[0];
    *(uint4*)(dt + nn * 32 + kk0 + 8) = *(uint4*)&o[8];
}

// ---- up: Hbuf[slot] = silu(x@w1g[e]) * (x@w1u[e]); TM=128 TN=64 ----------
__global__ __launch_bounds__(256) void up_mfma(
    const ushort* __restrict__ xb, const ushort* __restrict__ BgP,
    const ushort* __restrict__ BuP, const int* __restrict__ counts,
    const int* __restrict__ toks, ushort* __restrict__ Hbuf)
{
    const int e = blockIdx.z;
    const int cnt = counts[e];
    const int m0 = blockIdx.y * 128;
    if (m0 >= cnt) return;
    const int nb = blockIdx.x;
    const int tid = threadIdx.x;

    __shared__ ushort As[128][32];
    __shared__ ushort Bgs[64][32];
    __shared__ ushort Bus[64][32];
    __shared__ int rowslot[128];

    if (tid < 128) {
        int r = m0 + tid;
        rowslot[tid] = (r < cnt) ? toks[e * TOK + r] : -1;
    }
    __syncthreads();

    // A staging: 2 threads/row, each stores TWO uint4 (16 ushorts) -> full 32
    const int ar = tid >> 1;
    const int ac = (tid & 1) * 16;
    const int aslot = rowslot[ar];
    const ushort* aptr = xb + (size_t)(aslot < 0 ? 0 : (aslot >> 1)) * DDIM + ac;

    const int w = tid >> 6;
    const int lane = tid & 63;
    const int q = lane >> 4;
    const int l15 = lane & 15;
    const int wm = (w >> 1) * 64;
    const int wn = (w & 1) * 32;

    const ushort* bgt = BgP + ((size_t)(e * NB1 + nb) * KS1) * 2048 + w * 512 + lane * 8;
    const ushort* but = BuP + ((size_t)(e * NB1 + nb) * KS1) * 2048 + w * 512 + lane * 8;
    ushort* bgl = &Bgs[0][0] + w * 512;
    ushort* bul = &Bus[0][0] + w * 512;

    f32x4 accg[4][2], accu[4][2];
#pragma unroll
    for (int i = 0; i < 4; ++i)
#pragma unroll
        for (int j = 0; j < 2; ++j) { accg[i][j] = (f32x4)0.f; accu[i][j] = (f32x4)0.f; }

    for (int ks = 0; ks < KS1; ++ks) {
        uint4 av0 = *(const uint4*)(aptr + ks * 32);
        uint4 av1 = *(const uint4*)(aptr + ks * 32 + 8);
        __syncthreads();                       // prev compute done; LDS free
        gl2lds16(bgt + (size_t)ks * 2048, bgl);
        gl2lds16(but + (size_t)ks * 2048, bul);
        *(uint4*)&As[ar][ac]     = av0;
        *(uint4*)&As[ar][ac + 8] = av1;
        __syncthreads();                       // drains async B + A visible

        bf16x8 a[4], bg[2], bu[2];
#pragma unroll
        for (int mi = 0; mi < 4; ++mi)
            a[mi] = *(const bf16x8*)&As[wm + mi * 16 + l15][q * 8];
#pragma unroll
        for (int ni = 0; ni < 2; ++ni) {
            bg[ni] = *(const bf16x8*)&Bgs[wn + ni * 16 + l15][q * 8];
            bu[ni] = *(const bf16x8*)&Bus[wn + ni * 16 + l15][q * 8];
        }
#pragma unroll
        for (int mi = 0; mi < 4; ++mi)
#pragma unroll
            for (int ni = 0; ni < 2; ++ni) {
                accg[mi][ni] = __builtin_amdgcn_mfma_f32_16x16x32_bf16(a[mi], bg[ni], accg[mi][ni], 0, 0, 0);
                accu[mi][ni] = __builtin_amdgcn_mfma_f32_16x16x32_bf16(a[mi], bu[ni], accu[mi][ni], 0, 0, 0);
            }
    }

#pragma unroll
    for (int mi = 0; mi < 4; ++mi) {
#pragma unroll
        for (int r = 0; r < 4; ++r) {
            int ml = wm + mi * 16 + q * 4 + r;
            int slot = rowslot[ml];
            if (slot < 0) continue;
            ushort* hrow = Hbuf + (size_t)slot * HDIM + nb * 64 + wn + l15;
#pragma unroll
            for (int ni = 0; ni < 2; ++ni) {
                float g = accg[mi][ni][r];
                float u = accu[mi][ni][r];
                hrow[ni * 16] = cvt_bf16(silu_f(g) * u);
            }
        }
    }
}

// ---- down: Ybuf[slot] = Hbuf[slot] @ w2[e]; TM=128 TN=128, no atomics ----
__global__ __launch_bounds__(256) void down_mfma(
    const ushort* __restrict__ Hbuf, const ushort* __restrict__ W2P,
    const int* __restrict__ counts, const int* __restrict__ toks,
    float* __restrict__ Ybuf)
{
    const int e = blockIdx.z;
    const int cnt = counts[e];
    const int m0 = blockIdx.y * 128;
    if (m0 >= cnt) return;
    const int nb = blockIdx.x;
    const int tid = threadIdx.x;

    __shared__ ushort As[128][32];
    __shared__ ushort Bs[128][32];
    __shared__ int rowslot[128];

    if (tid < 128) {
        int r = m0 + tid;
        rowslot[tid] = (r < cnt) ? toks[e * TOK + r] : -1;
    }
    __syncthreads();

    const int ar = tid >> 1;
    const int ac = (tid & 1) * 16;
    const int aslot = rowslot[ar];
    const ushort* aptr = Hbuf + (size_t)(aslot < 0 ? 0 : aslot) * HDIM + ac;

    const int w = tid >> 6;
    const int lane = tid & 63;
    const int q = lane >> 4;
    const int l15 = lane & 15;
    const int wm = (w >> 1) * 64;
    const int wn = (w & 1) * 64;

    const ushort* bt = W2P + ((size_t)(e * NB2 + nb) * KS2) * 4096 + w * 1024 + lane * 8;
    ushort* bl = &Bs[0][0] + w * 1024;

    f32x4 acc[4][4];
#pragma unroll
    for (int i = 0; i < 4; ++i)
#pragma unroll
        for (int j = 0; j < 4; ++j) acc[i][j] = (f32x4)0.f;

    for (int ks = 0; ks < KS2; ++ks) {
        uint4 av0 = *(const uint4*)(aptr + ks * 32);
        uint4 av1 = *(const uint4*)(aptr + ks * 32 + 8);
        __syncthreads();
        gl2lds16(bt + (size_t)ks * 4096, bl);
        gl2lds16(bt + (size_t)ks * 4096 + 512, bl + 512);
        *(uint4*)&As[ar][ac]     = av0;
        *(uint4*)&As[ar][ac + 8] = av1;
        __syncthreads();

        bf16x8 a[4], b[4];
#pragma unroll
        for (int mi = 0; mi < 4; ++mi)
            a[mi] = *(const bf16x8*)&As[wm + mi * 16 + l15][q * 8];
#pragma unroll
        for (int ni = 0; ni < 4; ++ni)
            b[ni] = *(const bf16x8*)&Bs[wn + ni * 16 + l15][q * 8];
#pragma unroll
        for (int mi = 0; mi < 4; ++mi)
#pragma unroll
            for (int ni = 0; ni < 4; ++ni)
                acc[mi][ni] = __builtin_amdgcn_mfma_f32_16x16x32_bf16(a[mi], b[ni], acc[mi][ni], 0, 0, 0);
    }

#pragma unroll
    for (int mi = 0; mi < 4; ++mi) {
#pragma unroll
        for (int r = 0; r < 4; ++r) {
            int ml = wm + mi * 16 + q * 4 + r;
            int slot = rowslot[ml];
            if (slot < 0) continue;
            float* yr = Ybuf + (size_t)slot * DDIM + nb * 128 + wn + l15;
#pragma unroll
            for (int ni = 0; ni < 4; ++ni)
                yr[ni * 16] = acc[mi][ni][r];
        }
    }
}

// ---- combine: y[t] = w0*Ybuf[2t] + w1*Ybuf[2t+1] -------------------------
__global__ __launch_bounds__(256) void combine_kernel(
    const float* __restrict__ Ybuf, const float* __restrict__ wslot,
    float* __restrict__ y)
{
    const int t = blockIdx.x;
    const int j = threadIdx.x * 4;
    const float w0 = wslot[2 * t];
    const float w1 = wslot[2 * t + 1];
    float4 a = *(const float4*)(Ybuf + ((size_t)2 * t) * DDIM + j);
    float4 b = *(const float4*)(Ybuf + ((size_t)2 * t + 1) * DDIM + j);
    float4 o;
    o.x = w0 * a.x + w1 * b.x;
    o.y = w0 * a.y + w1 * b.y;
    o.z = w0 * a.z + w1 * b.z;
    o.w = w0 * a.w + w1 * b.w;
    *(float4*)(y + (size_t)t * DDIM + j) = o;
}

extern "C" void kernel_launch(void* const* d_in, const int* in_sizes, int n_in,
                              void* d_out, int out_size, void* d_ws, size_t ws_size,
                              hipStream_t stream) {
    const float* x   = (const float*)d_in[0];
    const float* gw  = (const float*)d_in[1];
    const float* w1g = (const float*)d_in[2];
    const float* w1u = (const float*)d_in[3];
    const float* w2  = (const float*)d_in[4];
    float* y = (float*)d_out;
    char* ws = (char*)d_ws;

    // workspace layout (Ybuf aliases BgP/BuP region — dead after up_mfma)
    size_t off = 0;
    int*    counts = (int*)(ws + off);   off += 256;
    int*    toks   = (int*)(ws + off);   off += (size_t)ENUM * TOK * 4;   // 64 KB
    float*  wslot  = (float*)(ws + off); off += (size_t)NSLOT * 4;        // 16 KB
    off = (off + 255) & ~(size_t)255;
    ushort* xb     = (ushort*)(ws + off); off += (size_t)TOK * DDIM * 2;  // 4 MB
    size_t regA = off;                                                    // 46 MB region
    ushort* BgP  = (ushort*)(ws + regA);
    ushort* BuP  = (ushort*)(ws + regA + (size_t)ENUM * DDIM * HDIM * 2);
    float*  Ybuf = (float*)(ws + regA);                                   // 16.8 MB alias
    off = regA + (size_t)2 * ENUM * DDIM * HDIM * 2;
    ushort* W2P  = (ushort*)(ws + off);  off += (size_t)ENUM * HDIM * DDIM * 2; // 23 MB
    ushort* Hbuf = (ushort*)(ws + off);                                         // 11.5 MB

    hipMemsetAsync(counts, 0, 256, stream);

    gate_kernel<<<TOK, 64, 0, stream>>>(x, gw, counts, toks, wslot, xb);

    tcast64_kernel <<<dim3(KS1, NB1, ENUM), 256, 0, stream>>>(w1g, BgP, HDIM, KS1, NB1);
    tcast64_kernel <<<dim3(KS1, NB1, ENUM), 256, 0, stream>>>(w1u, BuP, HDIM, KS1, NB1);
    tcast128_kernel<<<dim3(KS2, NB2, ENUM), 256, 0, stream>>>(w2,  W2P, DDIM, KS2, NB2);

    up_mfma<<<dim3(NB1, TOK / 128, ENUM), 256, 0, stream>>>(xb, BgP, BuP, counts, toks, Hbuf);
    down_mfma<<<dim3(NB2, TOK / 128, ENUM), 256, 0, stream>>>(Hbuf, W2P, counts, toks, Ybuf);
    combine_kernel<<<TOK, 256, 0, stream>>>(Ybuf, wslot, y);
}

// Round 5
// 316.070 us; speedup vs baseline: 2.5064x; 1.0457x over previous
//
#include <hip/hip_runtime.h>

#define TOK 2048
#define DDIM 1024
#define HDIM 1408
#define ENUM 8
#define NSLOT (2 * TOK)
#define UP_NB 22   // HDIM / 64
#define UP_KS 32   // DDIM / 32
#define DN_NB 16   // DDIM / 64
#define DN_KS 44   // HDIM / 32

typedef unsigned int uint;
typedef unsigned short ushort;

using bf16x8 = __attribute__((ext_vector_type(8))) __bf16;
using f32x4  = __attribute__((ext_vector_type(4))) float;

__device__ __forceinline__ float silu_f(float g) {
    return g / (1.0f + __expf(-g));
}

__device__ __forceinline__ ushort cvt_bf16(float f) {
    uint u = __float_as_uint(f);
    u += 0x7FFFu + ((u >> 16) & 1u);   // RNE
    return (ushort)(u >> 16);
}

// async global->LDS: per-lane global address, LDS dest = wave-uniform base + lane*16
__device__ __forceinline__ void gl2lds16(const void* g, void* l) {
    __builtin_amdgcn_global_load_lds(
        (const __attribute__((address_space(1))) uint*)g,
        (__attribute__((address_space(3))) uint*)l, 16, 0, 0);
}

// ---- gate: one wave/token; softmax top-2; also emits bf16 x row ----------
__global__ __launch_bounds__(64) void gate_kernel(
    const float* __restrict__ x, const float* __restrict__ gw,
    int* __restrict__ counts, int* __restrict__ toks,
    float* __restrict__ wslot, ushort* __restrict__ xb)
{
    const int t = blockIdx.x;
    const int lane = threadIdx.x;
    const float* xr = x + (size_t)t * DDIM;
    ushort* xbr = xb + (size_t)t * DDIM;
    float xv[16];
#pragma unroll
    for (int i = 0; i < 16; ++i) xv[i] = xr[lane + 64 * i];
#pragma unroll
    for (int i = 0; i < 16; ++i) xbr[lane + 64 * i] = cvt_bf16(xv[i]);
    float logit[ENUM];
#pragma unroll
    for (int e = 0; e < ENUM; ++e) {
        const float* gr = gw + (size_t)e * DDIM;
        float acc = 0.f;
#pragma unroll
        for (int i = 0; i < 16; ++i) acc += xv[i] * gr[lane + 64 * i];
#pragma unroll
        for (int s = 32; s > 0; s >>= 1) acc += __shfl_xor(acc, s, 64);
        logit[e] = acc;
    }
    if (lane == 0) {
        float mx = logit[0];
#pragma unroll
        for (int e = 1; e < ENUM; ++e) mx = fmaxf(mx, logit[e]);
        float p[ENUM]; float se = 0.f;
#pragma unroll
        for (int e = 0; e < ENUM; ++e) { p[e] = __expf(logit[e] - mx); se += p[e]; }
        float inv = 1.0f / se;
#pragma unroll
        for (int e = 0; e < ENUM; ++e) p[e] *= inv;
        int i0 = 0;
#pragma unroll
        for (int e = 1; e < ENUM; ++e) if (p[e] > p[i0]) i0 = e;
        int i1 = (i0 == 0) ? 1 : 0;
#pragma unroll
        for (int e = 0; e < ENUM; ++e) if (e != i0 && p[e] > p[i1]) i1 = e;
        int pos0 = atomicAdd(&counts[i0], 1);
        toks[i0 * TOK + pos0] = (t << 1);
        wslot[(t << 1)] = p[i0];
        int pos1 = atomicAdd(&counts[i1], 1);
        toks[i1 * TOK + pos1] = (t << 1) | 1;
        wslot[(t << 1) | 1] = p[i1];
    }
}

// ---- tcast64 body: fp32 [K][N] slab -> bf16 tiles [ks][nn(64)][kk(32)] ----
__device__ __forceinline__ void tcast64_body(
    const float* __restrict__ src, ushort* __restrict__ dst, int N, int KS, int NB,
    int e, int ks, int nb, int tid)
{
    __shared__ float Ls[32][68];
    const float* st = src + (size_t)e * ((size_t)KS * 32) * N + (size_t)(ks * 32) * N + nb * 64;
    const int n4 = (tid & 15) * 4;
#pragma unroll
    for (int r = 0; r < 2; ++r) {
        int k = (tid >> 4) + r * 16;
        float4 v = *(const float4*)(st + (size_t)k * N + n4);
        Ls[k][n4 + 0] = v.x; Ls[k][n4 + 1] = v.y; Ls[k][n4 + 2] = v.z; Ls[k][n4 + 3] = v.w;
    }
    __syncthreads();

    ushort* dt = dst + ((((size_t)e * NB + nb) * KS) + ks) * 2048;
    const int nn = tid >> 2;
    const int kk0 = (tid & 3) * 8;
    ushort o[8];
#pragma unroll
    for (int j = 0; j < 8; ++j) o[j] = cvt_bf16(Ls[kk0 + j][nn]);
    *(uint4*)(dt + nn * 32 + kk0) = *(uint4*)o;
}

// w1g + w1u fused (z = 0..15: low 3 bits expert, bit 3 selects tensor)
__global__ __launch_bounds__(256) void tcast_w1_kernel(
    const float* __restrict__ w1g, const float* __restrict__ w1u,
    ushort* __restrict__ BgP, ushort* __restrict__ BuP)
{
    const int z = blockIdx.z;
    const float* src = (z & 8) ? w1u : w1g;
    ushort* dst = (z & 8) ? BuP : BgP;
    tcast64_body(src, dst, HDIM, UP_KS, UP_NB, z & 7, blockIdx.x, blockIdx.y, threadIdx.x);
}

__global__ __launch_bounds__(256) void tcast_w2_kernel(
    const float* __restrict__ w2, ushort* __restrict__ W2P)
{
    tcast64_body(w2, W2P, DDIM, DN_KS, DN_NB, blockIdx.z, blockIdx.x, blockIdx.y, threadIdx.x);
}

// ---- up: Hbuf[slot] = silu(x@w1g[e]) * (x@w1u[e]); TM=64 TN=64, dbuf -----
__global__ __launch_bounds__(256, 4) void up_mfma(
    const ushort* __restrict__ xb, const ushort* __restrict__ BgP,
    const ushort* __restrict__ BuP, const int* __restrict__ counts,
    const int* __restrict__ toks, ushort* __restrict__ Hbuf)
{
    const int e = blockIdx.z;
    const int cnt = counts[e];
    const int m0 = blockIdx.y * 64;
    if (m0 >= cnt) return;
    const int nb = blockIdx.x;
    const int tid = threadIdx.x;
    const int w = tid >> 6;
    const int lane = tid & 63;
    const int q = lane >> 4;
    const int l15 = lane & 15;
    const int wr = w >> 1;   // 2x2 wave grid: wave tile 32m x 32n
    const int wc = w & 1;

    __shared__ ushort As[2][64][32];
    __shared__ ushort Bgs[2][64][32];
    __shared__ ushort Bus[2][64][32];
    __shared__ int rowslot[64];

    if (tid < 64) rowslot[tid] = (m0 + tid < cnt) ? toks[e * TOK + m0 + tid] : -1;
    __syncthreads();

    // per-lane A gather address: row = w*16 + (lane>>2), col = (lane&3)*8 elems
    const int arow = w * 16 + (lane >> 2);
    const int aslot = rowslot[arow];
    const ushort* agp = xb + (size_t)(aslot < 0 ? 0 : (aslot >> 1)) * DDIM + (lane & 3) * 8;
    // per-lane B addresses: tile is [64][32] = 2048 ushorts; wave covers 512
    const size_t bbase = ((size_t)(e * UP_NB + nb) * UP_KS) * 2048 + w * 512 + lane * 8;
    const ushort* bgp = BgP + bbase;
    const ushort* bup = BuP + bbase;

    f32x4 accg[2][2], accu[2][2];
#pragma unroll
    for (int i = 0; i < 2; ++i)
#pragma unroll
        for (int j = 0; j < 2; ++j) { accg[i][j] = (f32x4)0.f; accu[i][j] = (f32x4)0.f; }

#define UP_PREFETCH(KSV, B)                                   \
    {                                                         \
        gl2lds16(agp + (KSV) * 32, &As[B][w * 16][0]);        \
        gl2lds16(bgp + (size_t)(KSV) * 2048, &Bgs[B][w * 16][0]); \
        gl2lds16(bup + (size_t)(KSV) * 2048, &Bus[B][w * 16][0]); \
    }

    UP_PREFETCH(0, 0);
    __syncthreads();

    for (int ks = 0; ks < UP_KS; ++ks) {
        const int cur = ks & 1;
        const int nxt = cur ^ 1;
        if (ks + 1 < UP_KS) UP_PREFETCH(ks + 1, nxt);

        bf16x8 a[2], bg[2], bu[2];
#pragma unroll
        for (int mi = 0; mi < 2; ++mi)
            a[mi] = *(const bf16x8*)&As[cur][wr * 32 + mi * 16 + l15][q * 8];
#pragma unroll
        for (int ni = 0; ni < 2; ++ni) {
            bg[ni] = *(const bf16x8*)&Bgs[cur][wc * 32 + ni * 16 + l15][q * 8];
            bu[ni] = *(const bf16x8*)&Bus[cur][wc * 32 + ni * 16 + l15][q * 8];
        }
#pragma unroll
        for (int mi = 0; mi < 2; ++mi)
#pragma unroll
            for (int ni = 0; ni < 2; ++ni) {
                accg[mi][ni] = __builtin_amdgcn_mfma_f32_16x16x32_bf16(a[mi], bg[ni], accg[mi][ni], 0, 0, 0);
                accu[mi][ni] = __builtin_amdgcn_mfma_f32_16x16x32_bf16(a[mi], bu[ni], accu[mi][ni], 0, 0, 0);
            }
        __syncthreads();   // drains prefetch vmem + protects buffer swap
    }
#undef UP_PREFETCH

#pragma unroll
    for (int mi = 0; mi < 2; ++mi) {
#pragma unroll
        for (int r = 0; r < 4; ++r) {
            int ml = wr * 32 + mi * 16 + q * 4 + r;
            int slot = rowslot[ml];
            if (slot < 0) continue;
            ushort* hrow = Hbuf + (size_t)slot * HDIM + nb * 64 + wc * 32 + l15;
#pragma unroll
            for (int ni = 0; ni < 2; ++ni)
                hrow[ni * 16] = cvt_bf16(silu_f(accg[mi][ni][r]) * accu[mi][ni][r]);
        }
    }
}

// ---- down: Ybuf[slot] = Hbuf[slot] @ w2[e]; TM=64 TN=64, dbuf ------------
__global__ __launch_bounds__(256, 4) void down_mfma(
    const ushort* __restrict__ Hbuf, const ushort* __restrict__ W2P,
    const int* __restrict__ counts, const int* __restrict__ toks,
    float* __restrict__ Ybuf)
{
    const int e = blockIdx.z;
    const int cnt = counts[e];
    const int m0 = blockIdx.y * 64;
    if (m0 >= cnt) return;
    const int nb = blockIdx.x;
    const int tid = threadIdx.x;
    const int w = tid >> 6;
    const int lane = tid & 63;
    const int q = lane >> 4;
    const int l15 = lane & 15;
    const int wr = w >> 1;
    const int wc = w & 1;

    __shared__ ushort As[2][64][32];
    __shared__ ushort Bs[2][64][32];
    __shared__ int rowslot[64];

    if (tid < 64) rowslot[tid] = (m0 + tid < cnt) ? toks[e * TOK + m0 + tid] : -1;
    __syncthreads();

    const int arow = w * 16 + (lane >> 2);
    const int aslot = rowslot[arow];
    const ushort* agp = Hbuf + (size_t)(aslot < 0 ? 0 : aslot) * HDIM + (lane & 3) * 8;
    const ushort* bp = W2P + ((size_t)(e * DN_NB + nb) * DN_KS) * 2048 + w * 512 + lane * 8;

    f32x4 acc[2][2];
#pragma unroll
    for (int i = 0; i < 2; ++i)
#pragma unroll
        for (int j = 0; j < 2; ++j) acc[i][j] = (f32x4)0.f;

#define DN_PREFETCH(KSV, B)                                   \
    {                                                         \
        gl2lds16(agp + (KSV) * 32, &As[B][w * 16][0]);        \
        gl2lds16(bp + (size_t)(KSV) * 2048, &Bs[B][w * 16][0]); \
    }

    DN_PREFETCH(0, 0);
    __syncthreads();

    for (int ks = 0; ks < DN_KS; ++ks) {
        const int cur = ks & 1;
        const int nxt = cur ^ 1;
        if (ks + 1 < DN_KS) DN_PREFETCH(ks + 1, nxt);

        bf16x8 a[2], b[2];
#pragma unroll
        for (int mi = 0; mi < 2; ++mi)
            a[mi] = *(const bf16x8*)&As[cur][wr * 32 + mi * 16 + l15][q * 8];
#pragma unroll
        for (int ni = 0; ni < 2; ++ni)
            b[ni] = *(const bf16x8*)&Bs[cur][wc * 32 + ni * 16 + l15][q * 8];
#pragma unroll
        for (int mi = 0; mi < 2; ++mi)
#pragma unroll
            for (int ni = 0; ni < 2; ++ni)
                acc[mi][ni] = __builtin_amdgcn_mfma_f32_16x16x32_bf16(a[mi], b[ni], acc[mi][ni], 0, 0, 0);
        __syncthreads();
    }
#undef DN_PREFETCH

#pragma unroll
    for (int mi = 0; mi < 2; ++mi) {
#pragma unroll
        for (int r = 0; r < 4; ++r) {
            int ml = wr * 32 + mi * 16 + q * 4 + r;
            int slot = rowslot[ml];
            if (slot < 0) continue;
            float* yr = Ybuf + (size_t)slot * DDIM + nb * 64 + wc * 32 + l15;
#pragma unroll
            for (int ni = 0; ni < 2; ++ni)
                yr[ni * 16] = acc[mi][ni][r];
        }
    }
}

// ---- combine: y[t] = w0*Ybuf[2t] + w1*Ybuf[2t+1] -------------------------
__global__ __launch_bounds__(256) void combine_kernel(
    const float* __restrict__ Ybuf, const float* __restrict__ wslot,
    float* __restrict__ y)
{
    const int t = blockIdx.x;
    const int j = threadIdx.x * 4;
    const float w0 = wslot[2 * t];
    const float w1 = wslot[2 * t + 1];
    float4 a = *(const float4*)(Ybuf + ((size_t)2 * t) * DDIM + j);
    float4 b = *(const float4*)(Ybuf + ((size_t)2 * t + 1) * DDIM + j);
    float4 o;
    o.x = w0 * a.x + w1 * b.x;
    o.y = w0 * a.y + w1 * b.y;
    o.z = w0 * a.z + w1 * b.z;
    o.w = w0 * a.w + w1 * b.w;
    *(float4*)(y + (size_t)t * DDIM + j) = o;
}

extern "C" void kernel_launch(void* const* d_in, const int* in_sizes, int n_in,
                              void* d_out, int out_size, void* d_ws, size_t ws_size,
                              hipStream_t stream) {
    const float* x   = (const float*)d_in[0];
    const float* gw  = (const float*)d_in[1];
    const float* w1g = (const float*)d_in[2];
    const float* w1u = (const float*)d_in[3];
    const float* w2  = (const float*)d_in[4];
    float* y = (float*)d_out;
    char* ws = (char*)d_ws;

    // workspace layout (Ybuf aliases BgP/BuP region — dead after up_mfma)
    size_t off = 0;
    int*    counts = (int*)(ws + off);   off += 256;
    int*    toks   = (int*)(ws + off);   off += (size_t)ENUM * TOK * 4;   // 64 KB
    float*  wslot  = (float*)(ws + off); off += (size_t)NSLOT * 4;        // 16 KB
    off = (off + 255) & ~(size_t)255;
    ushort* xb     = (ushort*)(ws + off); off += (size_t)TOK * DDIM * 2;  // 4 MB
    size_t regA = off;                                                    // 46 MB region
    ushort* BgP  = (ushort*)(ws + regA);
    ushort* BuP  = (ushort*)(ws + regA + (size_t)ENUM * DDIM * HDIM * 2);
    float*  Ybuf = (float*)(ws + regA);                                   // 16.8 MB alias
    off = regA + (size_t)2 * ENUM * DDIM * HDIM * 2;
    ushort* W2P  = (ushort*)(ws + off);  off += (size_t)ENUM * HDIM * DDIM * 2; // 23 MB
    ushort* Hbuf = (ushort*)(ws + off);                                         // 11.5 MB

    hipMemsetAsync(counts, 0, 256, stream);

    gate_kernel<<<TOK, 64, 0, stream>>>(x, gw, counts, toks, wslot, xb);

    tcast_w1_kernel<<<dim3(UP_KS, UP_NB, 16), 256, 0, stream>>>(w1g, w1u, BgP, BuP);
    tcast_w2_kernel<<<dim3(DN_KS, DN_NB, ENUM), 256, 0, stream>>>(w2, W2P);

    up_mfma<<<dim3(UP_NB, TOK / 64, ENUM), 256, 0, stream>>>(xb, BgP, BuP, counts, toks, Hbuf);
    down_mfma<<<dim3(DN_NB, TOK / 64, ENUM), 256, 0, stream>>>(Hbuf, W2P, counts, toks, Ybuf);
    combine_kernel<<<TOK, 256, 0, stream>>>(Ybuf, wslot, y);
}

// Round 6
// 272.034 us; speedup vs baseline: 2.9121x; 1.1619x over previous
//
#include <hip/hip_runtime.h>

#define TOK 2048
#define DDIM 1024
#define HDIM 1408
#define ENUM 8
#define NSLOT (2 * TOK)
#define UP_NB 22   // HDIM / 64
#define UP_KS 32   // DDIM / 32
#define DN_NB 16   // DDIM / 64
#define DN_KS 44   // HDIM / 32

typedef unsigned int uint;
typedef unsigned short ushort;

using bf16x8 = __attribute__((ext_vector_type(8))) __bf16;
using f32x4  = __attribute__((ext_vector_type(4))) float;

__device__ __forceinline__ float silu_f(float g) {
    return g / (1.0f + __expf(-g));
}

__device__ __forceinline__ ushort cvt_bf16(float f) {
    uint u = __float_as_uint(f);
    u += 0x7FFFu + ((u >> 16) & 1u);   // RNE
    return (ushort)(u >> 16);
}

// async global->LDS: per-lane global address, LDS dest = wave-uniform base + lane*16
__device__ __forceinline__ void gl2lds16(const void* g, void* l) {
    __builtin_amdgcn_global_load_lds(
        (const __attribute__((address_space(1))) uint*)g,
        (__attribute__((address_space(3))) uint*)l, 16, 0, 0);
}

// ---- gate1: one wave/token; top-2 + weights; NO atomics; emits bf16 x ----
__global__ __launch_bounds__(64) void gate1_kernel(
    const float* __restrict__ x, const float* __restrict__ gw,
    int* __restrict__ tinfo, float* __restrict__ wslot, ushort* __restrict__ xb)
{
    const int t = blockIdx.x;
    const int lane = threadIdx.x;
    const float* xr = x + (size_t)t * DDIM;
    ushort* xbr = xb + (size_t)t * DDIM;
    float xv[16];
#pragma unroll
    for (int i = 0; i < 16; ++i) xv[i] = xr[lane + 64 * i];
#pragma unroll
    for (int i = 0; i < 16; ++i) xbr[lane + 64 * i] = cvt_bf16(xv[i]);
    float logit[ENUM];
#pragma unroll
    for (int e = 0; e < ENUM; ++e) {
        const float* gr = gw + (size_t)e * DDIM;
        float acc = 0.f;
#pragma unroll
        for (int i = 0; i < 16; ++i) acc += xv[i] * gr[lane + 64 * i];
#pragma unroll
        for (int s = 32; s > 0; s >>= 1) acc += __shfl_xor(acc, s, 64);
        logit[e] = acc;
    }
    if (lane == 0) {
        float mx = logit[0];
#pragma unroll
        for (int e = 1; e < ENUM; ++e) mx = fmaxf(mx, logit[e]);
        float p[ENUM]; float se = 0.f;
#pragma unroll
        for (int e = 0; e < ENUM; ++e) { p[e] = __expf(logit[e] - mx); se += p[e]; }
        float inv = 1.0f / se;
#pragma unroll
        for (int e = 0; e < ENUM; ++e) p[e] *= inv;
        int i0 = 0;
#pragma unroll
        for (int e = 1; e < ENUM; ++e) if (p[e] > p[i0]) i0 = e;
        int i1 = (i0 == 0) ? 1 : 0;
#pragma unroll
        for (int e = 0; e < ENUM; ++e) if (e != i0 && p[e] > p[i1]) i1 = e;
        tinfo[t] = i0 | (i1 << 4);
        wslot[(t << 1)] = p[i0];
        wslot[(t << 1) | 1] = p[i1];
    }
}

// ---- gate2: single block builds all expert lists with LDS atomics --------
__global__ __launch_bounds__(256) void gate2_kernel(
    const int* __restrict__ tinfo, int* __restrict__ counts, int* __restrict__ toks)
{
    __shared__ int cnt[ENUM];
    const int tid = threadIdx.x;
    if (tid < ENUM) cnt[tid] = 0;
    __syncthreads();
    for (int t = tid; t < TOK; t += 256) {
        int info = tinfo[t];
        int i0 = info & 15, i1 = info >> 4;
        int p0 = atomicAdd(&cnt[i0], 1);
        toks[i0 * TOK + p0] = (t << 1);
        int p1 = atomicAdd(&cnt[i1], 1);
        toks[i1 * TOK + p1] = (t << 1) | 1;
    }
    __syncthreads();
    if (tid < ENUM) counts[tid] = cnt[tid];
}

// ---- tcast64 body: fp32 [K][N] slab -> bf16 tiles [ks][nn(64)][kk(32)] ----
__device__ __forceinline__ void tcast64_body(
    const float* __restrict__ src, ushort* __restrict__ dst, int N, int KS, int NB,
    int e, int ks, int nb, int tid)
{
    __shared__ float Ls[32][68];
    const float* st = src + (size_t)e * ((size_t)KS * 32) * N + (size_t)(ks * 32) * N + nb * 64;
    const int n4 = (tid & 15) * 4;
#pragma unroll
    for (int r = 0; r < 2; ++r) {
        int k = (tid >> 4) + r * 16;
        float4 v = *(const float4*)(st + (size_t)k * N + n4);
        Ls[k][n4 + 0] = v.x; Ls[k][n4 + 1] = v.y; Ls[k][n4 + 2] = v.z; Ls[k][n4 + 3] = v.w;
    }
    __syncthreads();

    ushort* dt = dst + ((((size_t)e * NB + nb) * KS) + ks) * 2048;
    const int nn = tid >> 2;
    const int kk0 = (tid & 3) * 8;
    ushort o[8];
#pragma unroll
    for (int j = 0; j < 8; ++j) o[j] = cvt_bf16(Ls[kk0 + j][nn]);
    *(uint4*)(dt + nn * 32 + kk0) = *(uint4*)o;
}

// w1g + w1u fused (z = 0..15: low 3 bits expert, bit 3 selects tensor)
__global__ __launch_bounds__(256) void tcast_w1_kernel(
    const float* __restrict__ w1g, const float* __restrict__ w1u,
    ushort* __restrict__ BgP, ushort* __restrict__ BuP)
{
    const int z = blockIdx.z;
    const float* src = (z & 8) ? w1u : w1g;
    ushort* dst = (z & 8) ? BuP : BgP;
    tcast64_body(src, dst, HDIM, UP_KS, UP_NB, z & 7, blockIdx.x, blockIdx.y, threadIdx.x);
}

__global__ __launch_bounds__(256) void tcast_w2_kernel(
    const float* __restrict__ w2, ushort* __restrict__ W2P)
{
    tcast64_body(w2, W2P, DDIM, DN_KS, DN_NB, blockIdx.z, blockIdx.x, blockIdx.y, threadIdx.x);
}

// ---- up: Hbuf[slot] = silu(x@w1g[e]) * (x@w1u[e]); TM=64 TN=64, dbuf,
//      XOR-swizzled LDS (phys16Bchunk = (logical + (row>>1)) & 3) ----------
__global__ __launch_bounds__(256, 4) void up_mfma(
    const ushort* __restrict__ xb, const ushort* __restrict__ BgP,
    const ushort* __restrict__ BuP, const int* __restrict__ counts,
    const int* __restrict__ toks, ushort* __restrict__ Hbuf)
{
    const int e = blockIdx.z;
    const int cnt = counts[e];
    const int m0 = blockIdx.y * 64;
    if (m0 >= cnt) return;
    const int nb = blockIdx.x;
    const int tid = threadIdx.x;
    const int w = tid >> 6;
    const int lane = tid & 63;
    const int q = lane >> 4;
    const int l15 = lane & 15;
    const int wr = w >> 1;   // 2x2 wave grid: wave tile 32m x 32n
    const int wc = w & 1;

    __shared__ ushort As[2][64][32];
    __shared__ ushort Bgs[2][64][32];
    __shared__ ushort Bus[2][64][32];
    __shared__ int rowslot[64];

    if (tid < 64) rowslot[tid] = (m0 + tid < cnt) ? toks[e * TOK + m0 + tid] : -1;
    __syncthreads();

    // staging: lane's LDS slot is row srow=(w*16+lane>>2), phys chunk lane&3;
    // fetch the LOGICAL chunk that belongs there: clog = (phys - (srow>>1)) & 3
    const int srow = w * 16 + (lane >> 2);
    const int clog = (((lane & 3) + 4 - ((srow >> 1) & 3)) & 3) * 8;
    const int aslot = rowslot[srow];
    const ushort* agp = xb + (size_t)(aslot < 0 ? 0 : (aslot >> 1)) * DDIM + clog;
    const size_t tb = (size_t)(e * UP_NB + nb) * UP_KS * 2048;
    const ushort* bgp = BgP + tb + srow * 32 + clog;
    const ushort* bup = BuP + tb + srow * 32 + clog;

    // reads: lane-constant swizzled chunk offset
    const int coff = ((q + (l15 >> 1)) & 3) * 8;

    f32x4 accg[2][2], accu[2][2];
#pragma unroll
    for (int i = 0; i < 2; ++i)
#pragma unroll
        for (int j = 0; j < 2; ++j) { accg[i][j] = (f32x4)0.f; accu[i][j] = (f32x4)0.f; }

#define UP_PREFETCH(KSV, B)                                       \
    {                                                             \
        gl2lds16(agp + (KSV) * 32, &As[B][w * 16][0]);            \
        gl2lds16(bgp + (size_t)(KSV) * 2048, &Bgs[B][w * 16][0]); \
        gl2lds16(bup + (size_t)(KSV) * 2048, &Bus[B][w * 16][0]); \
    }

    UP_PREFETCH(0, 0);
    __syncthreads();

    for (int ks = 0; ks < UP_KS; ++ks) {
        const int cur = ks & 1;
        const int nxt = cur ^ 1;
        if (ks + 1 < UP_KS) UP_PREFETCH(ks + 1, nxt);

        bf16x8 a[2], bg[2], bu[2];
#pragma unroll
        for (int mi = 0; mi < 2; ++mi)
            a[mi] = *(const bf16x8*)&As[cur][wr * 32 + mi * 16 + l15][coff];
#pragma unroll
        for (int ni = 0; ni < 2; ++ni) {
            bg[ni] = *(const bf16x8*)&Bgs[cur][wc * 32 + ni * 16 + l15][coff];
            bu[ni] = *(const bf16x8*)&Bus[cur][wc * 32 + ni * 16 + l15][coff];
        }
#pragma unroll
        for (int mi = 0; mi < 2; ++mi)
#pragma unroll
            for (int ni = 0; ni < 2; ++ni) {
                accg[mi][ni] = __builtin_amdgcn_mfma_f32_16x16x32_bf16(a[mi], bg[ni], accg[mi][ni], 0, 0, 0);
                accu[mi][ni] = __builtin_amdgcn_mfma_f32_16x16x32_bf16(a[mi], bu[ni], accu[mi][ni], 0, 0, 0);
            }
        __syncthreads();   // drains prefetch vmem + protects buffer swap
    }
#undef UP_PREFETCH

#pragma unroll
    for (int mi = 0; mi < 2; ++mi) {
#pragma unroll
        for (int r = 0; r < 4; ++r) {
            int ml = wr * 32 + mi * 16 + q * 4 + r;
            int slot = rowslot[ml];
            if (slot < 0) continue;
            ushort* hrow = Hbuf + (size_t)slot * HDIM + nb * 64 + wc * 32 + l15;
#pragma unroll
            for (int ni = 0; ni < 2; ++ni)
                hrow[ni * 16] = cvt_bf16(silu_f(accg[mi][ni][r]) * accu[mi][ni][r]);
        }
    }
}

// ---- down: Ybuf[slot] = Hbuf[slot] @ w2[e]; TM=64 TN=64, dbuf, swizzled --
__global__ __launch_bounds__(256, 4) void down_mfma(
    const ushort* __restrict__ Hbuf, const ushort* __restrict__ W2P,
    const int* __restrict__ counts, const int* __restrict__ toks,
    float* __restrict__ Ybuf)
{
    const int e = blockIdx.z;
    const int cnt = counts[e];
    const int m0 = blockIdx.y * 64;
    if (m0 >= cnt) return;
    const int nb = blockIdx.x;
    const int tid = threadIdx.x;
    const int w = tid >> 6;
    const int lane = tid & 63;
    const int q = lane >> 4;
    const int l15 = lane & 15;
    const int wr = w >> 1;
    const int wc = w & 1;

    __shared__ ushort As[2][64][32];
    __shared__ ushort Bs[2][64][32];
    __shared__ int rowslot[64];

    if (tid < 64) rowslot[tid] = (m0 + tid < cnt) ? toks[e * TOK + m0 + tid] : -1;
    __syncthreads();

    const int srow = w * 16 + (lane >> 2);
    const int clog = (((lane & 3) + 4 - ((srow >> 1) & 3)) & 3) * 8;
    const int aslot = rowslot[srow];
    const ushort* agp = Hbuf + (size_t)(aslot < 0 ? 0 : aslot) * HDIM + clog;
    const ushort* bp = W2P + (size_t)(e * DN_NB + nb) * DN_KS * 2048 + srow * 32 + clog;

    const int coff = ((q + (l15 >> 1)) & 3) * 8;

    f32x4 acc[2][2];
#pragma unroll
    for (int i = 0; i < 2; ++i)
#pragma unroll
        for (int j = 0; j < 2; ++j) acc[i][j] = (f32x4)0.f;

#define DN_PREFETCH(KSV, B)                                     \
    {                                                           \
        gl2lds16(agp + (KSV) * 32, &As[B][w * 16][0]);          \
        gl2lds16(bp + (size_t)(KSV) * 2048, &Bs[B][w * 16][0]); \
    }

    DN_PREFETCH(0, 0);
    __syncthreads();

    for (int ks = 0; ks < DN_KS; ++ks) {
        const int cur = ks & 1;
        const int nxt = cur ^ 1;
        if (ks + 1 < DN_KS) DN_PREFETCH(ks + 1, nxt);

        bf16x8 a[2], b[2];
#pragma unroll
        for (int mi = 0; mi < 2; ++mi)
            a[mi] = *(const bf16x8*)&As[cur][wr * 32 + mi * 16 + l15][coff];
#pragma unroll
        for (int ni = 0; ni < 2; ++ni)
            b[ni] = *(const bf16x8*)&Bs[cur][wc * 32 + ni * 16 + l15][coff];
#pragma unroll
        for (int mi = 0; mi < 2; ++mi)
#pragma unroll
            for (int ni = 0; ni < 2; ++ni)
                acc[mi][ni] = __builtin_amdgcn_mfma_f32_16x16x32_bf16(a[mi], b[ni], acc[mi][ni], 0, 0, 0);
        __syncthreads();
    }
#undef DN_PREFETCH

#pragma unroll
    for (int mi = 0; mi < 2; ++mi) {
#pragma unroll
        for (int r = 0; r < 4; ++r) {
            int ml = wr * 32 + mi * 16 + q * 4 + r;
            int slot = rowslot[ml];
            if (slot < 0) continue;
            float* yr = Ybuf + (size_t)slot * DDIM + nb * 64 + wc * 32 + l15;
#pragma unroll
            for (int ni = 0; ni < 2; ++ni)
                yr[ni * 16] = acc[mi][ni][r];
        }
    }
}

// ---- combine: y[t] = w0*Ybuf[2t] + w1*Ybuf[2t+1] -------------------------
__global__ __launch_bounds__(256) void combine_kernel(
    const float* __restrict__ Ybuf, const float* __restrict__ wslot,
    float* __restrict__ y)
{
    const int t = blockIdx.x;
    const int j = threadIdx.x * 4;
    const float w0 = wslot[2 * t];
    const float w1 = wslot[2 * t + 1];
    float4 a = *(const float4*)(Ybuf + ((size_t)2 * t) * DDIM + j);
    float4 b = *(const float4*)(Ybuf + ((size_t)2 * t + 1) * DDIM + j);
    float4 o;
    o.x = w0 * a.x + w1 * b.x;
    o.y = w0 * a.y + w1 * b.y;
    o.z = w0 * a.z + w1 * b.z;
    o.w = w0 * a.w + w1 * b.w;
    *(float4*)(y + (size_t)t * DDIM + j) = o;
}

extern "C" void kernel_launch(void* const* d_in, const int* in_sizes, int n_in,
                              void* d_out, int out_size, void* d_ws, size_t ws_size,
                              hipStream_t stream) {
    const float* x   = (const float*)d_in[0];
    const float* gw  = (const float*)d_in[1];
    const float* w1g = (const float*)d_in[2];
    const float* w1u = (const float*)d_in[3];
    const float* w2  = (const float*)d_in[4];
    float* y = (float*)d_out;
    char* ws = (char*)d_ws;

    // workspace layout (Ybuf aliases BgP/BuP region — dead after up_mfma)
    size_t off = 0;
    int*    counts = (int*)(ws + off);   off += 256;
    int*    toks   = (int*)(ws + off);   off += (size_t)ENUM * TOK * 4;   // 64 KB
    float*  wslot  = (float*)(ws + off); off += (size_t)NSLOT * 4;        // 16 KB
    int*    tinfo  = (int*)(ws + off);   off += (size_t)TOK * 4;          // 8 KB
    off = (off + 255) & ~(size_t)255;
    ushort* xb     = (ushort*)(ws + off); off += (size_t)TOK * DDIM * 2;  // 4 MB
    size_t regA = off;                                                    // 46 MB region
    ushort* BgP  = (ushort*)(ws + regA);
    ushort* BuP  = (ushort*)(ws + regA + (size_t)ENUM * DDIM * HDIM * 2);
    float*  Ybuf = (float*)(ws + regA);                                   // 16.8 MB alias
    off = regA + (size_t)2 * ENUM * DDIM * HDIM * 2;
    ushort* W2P  = (ushort*)(ws + off);  off += (size_t)ENUM * HDIM * DDIM * 2; // 23 MB
    ushort* Hbuf = (ushort*)(ws + off);                                         // 11.5 MB

    gate1_kernel<<<TOK, 64, 0, stream>>>(x, gw, tinfo, wslot, xb);
    gate2_kernel<<<1, 256, 0, stream>>>(tinfo, counts, toks);

    tcast_w1_kernel<<<dim3(UP_KS, UP_NB, 16), 256, 0, stream>>>(w1g, w1u, BgP, BuP);
    tcast_w2_kernel<<<dim3(DN_KS, DN_NB, ENUM), 256, 0, stream>>>(w2, W2P);

    up_mfma<<<dim3(UP_NB, TOK / 64, ENUM), 256, 0, stream>>>(xb, BgP, BuP, counts, toks, Hbuf);
    down_mfma<<<dim3(DN_NB, TOK / 64, ENUM), 256, 0, stream>>>(Hbuf, W2P, counts, toks, Ybuf);
    combine_kernel<<<TOK, 256, 0, stream>>>(Ybuf, wslot, y);
}